// Round 4
// baseline (5424.788 us; speedup 1.0000x reference)
//
#include <hip/hip_runtime.h>
#include <hip/hip_bf16.h>

#define NH 16
#define HD 64
#define ED 1024
#define BS 4
#define SL 2048

typedef _Float16 f16x8 __attribute__((ext_vector_type(8)));
typedef float floatx4 __attribute__((ext_vector_type(4)));

// ---------------------------------------------------------------------------
// GEMM: C = A[MxK] * B[NxK]^T. fp32 global inputs converted to fp16 during
// LDS staging; MFMA f32_16x16x32_f16; fp32 accumulate.
// 64x64 tile per 256-thread block; 4 waves 2x2, each wave 32x32 (2x2 mfma).
// LDS fragment-contiguous: lane's 16B fragment at lds[(mt*64+lane)*8].
// A_MODE 0: A fp32 row-major [M x K]
// A_MODE 1: A fp16 [b,h,s,d]  (row = b*SL+s, k = h*64+d) — attn-out gather
// OUT_MODE 0: fp16 scatter to [b,h,s,d]
// OUT_MODE 1: fp32 row-major [M x N]
// ---------------------------------------------------------------------------
template <int A_MODE, int OUT_MODE>
__device__ __forceinline__ void gemm_bt_body(const float* __restrict__ Af,
                                             const _Float16* __restrict__ Ah,
                                             const float* __restrict__ B,
                                             _Float16* __restrict__ outH,
                                             float* __restrict__ outF,
                                             int K, int N)
{
    __shared__ __align__(16) _Float16 As[64 * 32];
    __shared__ __align__(16) _Float16 Bs[64 * 32];

    const int tid  = threadIdx.x;
    const int wave = tid >> 6;
    const int lane = tid & 63;
    const int wm = wave >> 1;
    const int wn = wave & 1;
    const int rowTile = blockIdx.y * 64;
    const int colTile = blockIdx.x * 64;

    // staging: thread t covers 8 k's of one tile row (A and B)
    const int sRow  = tid >> 2;   // 0..63 tile row
    const int sQuad = tid & 3;    // which k-octet
    const int ldsOff = ((sRow >> 4) * 64 + (sRow & 15) + 16 * sQuad) * 8;

    const int aRow = rowTile + sRow;
    const int aB = aRow >> 11;          // / SL
    const int aS = aRow & (SL - 1);

    floatx4 acc00 = {0.f, 0.f, 0.f, 0.f};
    floatx4 acc01 = {0.f, 0.f, 0.f, 0.f};
    floatx4 acc10 = {0.f, 0.f, 0.f, 0.f};
    floatx4 acc11 = {0.f, 0.f, 0.f, 0.f};

    for (int kb = 0; kb < K; kb += 32) {
        const int k0 = kb + sQuad * 8;
        f16x8 av;
        if (A_MODE == 0) {
            float4 a0 = *(const float4*)(Af + (size_t)aRow * K + k0);
            float4 a1 = *(const float4*)(Af + (size_t)aRow * K + k0 + 4);
            av[0] = (_Float16)a0.x; av[1] = (_Float16)a0.y;
            av[2] = (_Float16)a0.z; av[3] = (_Float16)a0.w;
            av[4] = (_Float16)a1.x; av[5] = (_Float16)a1.y;
            av[6] = (_Float16)a1.z; av[7] = (_Float16)a1.w;
        } else {
            // fp16 gather from [b,h,s,d]; 8 consecutive d's
            av = *(const f16x8*)(Ah + ((((size_t)(aB * NH + (k0 >> 6))) * SL + aS) * HD + (k0 & (HD - 1))));
        }
        float4 b0 = *(const float4*)(B + (size_t)(colTile + sRow) * K + k0);
        float4 b1 = *(const float4*)(B + (size_t)(colTile + sRow) * K + k0 + 4);
        f16x8 bv;
        bv[0] = (_Float16)b0.x; bv[1] = (_Float16)b0.y;
        bv[2] = (_Float16)b0.z; bv[3] = (_Float16)b0.w;
        bv[4] = (_Float16)b1.x; bv[5] = (_Float16)b1.y;
        bv[6] = (_Float16)b1.z; bv[7] = (_Float16)b1.w;

        __syncthreads();                       // protect prior frag reads
        *(f16x8*)(As + ldsOff) = av;
        *(f16x8*)(Bs + ldsOff) = bv;
        __syncthreads();
        f16x8 a0v = *(const f16x8*)(As + ((wm * 2 + 0) * 64 + lane) * 8);
        f16x8 a1v = *(const f16x8*)(As + ((wm * 2 + 1) * 64 + lane) * 8);
        f16x8 b0v = *(const f16x8*)(Bs + ((wn * 2 + 0) * 64 + lane) * 8);
        f16x8 b1v = *(const f16x8*)(Bs + ((wn * 2 + 1) * 64 + lane) * 8);
        acc00 = __builtin_amdgcn_mfma_f32_16x16x32_f16(a0v, b0v, acc00, 0, 0, 0);
        acc01 = __builtin_amdgcn_mfma_f32_16x16x32_f16(a0v, b1v, acc01, 0, 0, 0);
        acc10 = __builtin_amdgcn_mfma_f32_16x16x32_f16(a1v, b0v, acc10, 0, 0, 0);
        acc11 = __builtin_amdgcn_mfma_f32_16x16x32_f16(a1v, b1v, acc11, 0, 0, 0);
    }

    // epilogue: C/D layout col=lane&15, row=(lane>>4)*4+reg
    const int rBase = rowTile + wm * 32 + ((lane >> 4) * 4);
    const int cBase = colTile + wn * 32 + (lane & 15);
    floatx4 accs[2][2] = {{acc00, acc01}, {acc10, acc11}};
#pragma unroll
    for (int mi = 0; mi < 2; mi++) {
#pragma unroll
        for (int ni = 0; ni < 2; ni++) {
            int col = cBase + ni * 16;
#pragma unroll
            for (int i = 0; i < 4; i++) {
                int row = rBase + mi * 16 + i;
                float v = accs[mi][ni][i];
                if (OUT_MODE == 0) {
                    int b = row >> 11;          // / SL
                    int s = row & (SL - 1);
                    int h = col >> 6;           // / HD
                    int d = col & (HD - 1);
                    outH[(((size_t)(b * NH + h)) * SL + s) * HD + d] = (_Float16)v;
                } else {
                    outF[(size_t)row * N + col] = v;
                }
            }
        }
    }
}

__global__ __launch_bounds__(256) void qkv_kernel(const float* __restrict__ x,
                                                  const float* __restrict__ Wq,
                                                  const float* __restrict__ Wk,
                                                  const float* __restrict__ Wv,
                                                  _Float16* __restrict__ Q,
                                                  _Float16* __restrict__ Kk,
                                                  _Float16* __restrict__ V)
{
    const float* W = (blockIdx.z == 0) ? Wq : (blockIdx.z == 1) ? Wk : Wv;
    _Float16* out = (blockIdx.z == 0) ? Q : (blockIdx.z == 1) ? Kk : V;
    gemm_bt_body<0, 0>(x, nullptr, W, out, nullptr, ED, ED);
}

__global__ __launch_bounds__(256) void oproj_kernel(const _Float16* __restrict__ A,
                                                    const float* __restrict__ Wo,
                                                    float* __restrict__ out)
{
    gemm_bt_body<1, 1>(nullptr, A, Wo, nullptr, out, ED, ED);
}

// ---------------------------------------------------------------------------
// Flash-style attention, fp32 vector math, fp16 Q/K/V, fp32 bias.
// Block = 256 threads = 4 waves; wave w owns q-row (blockIdx.y*4 + w).
// Grid = (BS, SL/4, NH): consecutive blocks share the same bias row across
// batch (bias has no batch dim) -> L3 temporal locality.
// K chunk staged row-major fp32 (stride 66); V staged transposed Vt[d][key].
// Online softmax via wave shuffles; output fp16 [b,h,s,d] to attnOut.
// ---------------------------------------------------------------------------
__global__ __launch_bounds__(256) void attn_kernel(const _Float16* __restrict__ Qg,
                                                   const _Float16* __restrict__ Kg,
                                                   const _Float16* __restrict__ Vg,
                                                   const float* __restrict__ bias,
                                                   _Float16* __restrict__ attnOut)
{
    __shared__ __align__(16) float Kc[64 * 66];
    __shared__ __align__(16) float Vt[64 * 66];
    __shared__ __align__(16) float qs[4 * 64];
    __shared__ __align__(16) float ps[4 * 64];

    const int b = blockIdx.x;           // 0..3
    const int h = blockIdx.z;           // 0..15
    const int bh = b * NH + h;
    const int row0 = blockIdx.y * 4;
    const int tid = threadIdx.x;
    const int wave = tid >> 6;
    const int lane = tid & 63;
    const int row = row0 + wave;

    const _Float16* Qbh = Qg + (size_t)bh * SL * HD;
    const _Float16* Kbh = Kg + (size_t)bh * SL * HD;
    const _Float16* Vbh = Vg + (size_t)bh * SL * HD;

    // load the 4 q rows: qs[wave*64+lane] = Q[row][lane]
    qs[tid] = (float)Qbh[(size_t)row * HD + lane];

    float m = -1e30f;
    float l = 0.f;
    float O = 0.f;

    const int sKey = tid >> 2;          // 0..63
    const int sD = (tid & 3) * 16;      // 0,16,32,48

    const float* biasRow = bias + (size_t)h * SL * SL + (size_t)row * SL;

    for (int kc = 0; kc < SL; kc += 64) {
        __syncthreads();                // prior chunk's reads done
        // ---- stage K rows (each thread: 16 consecutive fp16 = 32B) ----
        const _Float16* kSrc = Kbh + (size_t)(kc + sKey) * HD + sD;
        f16x8 kv0 = *(const f16x8*)(kSrc);
        f16x8 kv1 = *(const f16x8*)(kSrc + 8);
        float2* kDst = (float2*)(Kc + sKey * 66 + sD);   // 8B aligned
#pragma unroll
        for (int i = 0; i < 4; i++)
            kDst[i] = make_float2((float)kv0[2 * i], (float)kv0[2 * i + 1]);
#pragma unroll
        for (int i = 0; i < 4; i++)
            kDst[4 + i] = make_float2((float)kv1[2 * i], (float)kv1[2 * i + 1]);
        // ---- stage V transposed ----
        const _Float16* vSrc = Vbh + (size_t)(kc + sKey) * HD + sD;
        f16x8 vv0 = *(const f16x8*)(vSrc);
        f16x8 vv1 = *(const f16x8*)(vSrc + 8);
#pragma unroll
        for (int i = 0; i < 8; i++)
            Vt[(sD + i) * 66 + sKey] = (float)vv0[i];
#pragma unroll
        for (int i = 0; i < 8; i++)
            Vt[(sD + 8 + i) * 66 + sKey] = (float)vv1[i];
        __syncthreads();

        // ---- scores: lane j = key kc+j ----
        float s = 0.f;
        const float2* kRow = (const float2*)(Kc + lane * 66);
        const float2* qRow = (const float2*)(qs + wave * 64);
#pragma unroll
        for (int i = 0; i < 32; i++) {
            float2 kk = kRow[i];
            float2 qq = qRow[i];
            s += kk.x * qq.x + kk.y * qq.y;
        }
        s += biasRow[kc + lane];        // T5: unscaled + additive bias

        // ---- online softmax ----
        float cm = s;
#pragma unroll
        for (int off = 32; off; off >>= 1) cm = fmaxf(cm, __shfl_xor(cm, off));
        float mNew = fmaxf(m, cm);
        float alpha = __expf(m - mNew);
        float p = __expf(s - mNew);
        float psum = p;
#pragma unroll
        for (int off = 32; off; off >>= 1) psum += __shfl_xor(psum, off);
        l = l * alpha + psum;
        m = mNew;
        O *= alpha;
        ps[wave * 64 + lane] = p;

        // ---- PV: lane = d, read Vt row d over keys ----
        const float2* vRow = (const float2*)(Vt + lane * 66);
        const float2* pRow = (const float2*)(ps + wave * 64);
#pragma unroll
        for (int i = 0; i < 32; i++) {
            float2 vv = vRow[i];
            float2 pp = pRow[i];
            O += vv.x * pp.x + vv.y * pp.y;
        }
    }

    // attn output fp16, layout [b,h,s,d]
    attnOut[((size_t)bh * SL + row) * HD + lane] = (_Float16)(O / l);
}

extern "C" void kernel_launch(void* const* d_in, const int* in_sizes, int n_in,
                              void* d_out, int out_size, void* d_ws, size_t ws_size,
                              hipStream_t stream)
{
    (void)in_sizes; (void)n_in; (void)out_size; (void)ws_size;

    const float* x    = (const float*)d_in[0];
    const float* bias = (const float*)d_in[1];
    const float* Wq   = (const float*)d_in[2];
    const float* Wk   = (const float*)d_in[3];
    const float* Wv   = (const float*)d_in[4];
    const float* Wo   = (const float*)d_in[5];

    const size_t nQKV = (size_t)BS * NH * SL * HD;   // 8388608 elements
    // Q,K (fp16) live inside d_out (exactly 2*16.78MB = 33.55MB = out bytes).
    // V + attn-out (fp16) live in ws (33.55MB total). O-proj overwrites d_out.
    _Float16* Qh = (_Float16*)d_out;
    _Float16* Kh = Qh + nQKV;
    _Float16* Vh = (_Float16*)d_ws;
    _Float16* attnH = Vh + nQKV;

    // 1) QKV projections: [8192x1024] @ W^T -> fp16 [b,h,s,d]
    dim3 gq(ED / 64, (BS * SL) / 64, 3);
    qkv_kernel<<<gq, 256, 0, stream>>>(x, Wq, Wk, Wv, Qh, Kh, Vh);

    // 2) fused attention with rel-pos bias -> fp16 [b,h,s,d]
    dim3 ga(BS, SL / 4, NH);
    attn_kernel<<<ga, 256, 0, stream>>>(Qh, Kh, Vh, bias, attnH);

    // 3) output projection (gather A from [b,h,s,d]) -> d_out fp32 [8192x1024]
    dim3 go(ED / 64, (BS * SL) / 64);
    oproj_kernel<<<go, 256, 0, stream>>>(attnH, Wo, (float*)d_out);
}